// Round 7
// baseline (130.615 us; speedup 1.0000x reference)
//
#include <hip/hip_runtime.h>

#define NCLS 30000

__device__ __forceinline__ unsigned short f2bf(float x) {
    unsigned int u = __float_as_uint(x);
    unsigned int r = (u + 0x7fffu + ((u >> 16) & 1u)) >> 16;   // RNE
    return (unsigned short)r;
}

// ---- transpose logits [M][N] -> flatTb [N][M] in bf16 (M=128);
// ---- blockIdx.y==0 slabs also zero the counts array (done before count pass)
__global__ void transpose_in_kernel(const float* __restrict__ src,
                                    unsigned short* __restrict__ dst,
                                    int* __restrict__ counts, int n, int m) {
    __shared__ float tile[32][33];
    int n0 = blockIdx.x * 32;
    int m0 = blockIdx.y * 32;
    int tx = threadIdx.x, ty = threadIdx.y;   // 32 x 8 threads

    if (blockIdx.y == 0) {
        int t = blockIdx.x * 256 + ty * 32 + tx;
        if (t < n) counts[t] = 0;
    }
#pragma unroll
    for (int k = 0; k < 4; ++k) {
        int mm = m0 + ty + k * 8;
        int nn = n0 + tx;
        if (nn < n) tile[ty + k * 8][tx] = src[(size_t)mm * n + nn];
    }
    __syncthreads();
#pragma unroll
    for (int k = 0; k < 4; ++k) {
        int nn = n0 + ty + k * 8;
        int mm = m0 + tx;
        if (nn < n) dst[(size_t)nn * m + mm] = f2bf(tile[tx][ty + k * 8]);
    }
}

// 4 edges per thread, vectorized row load
__global__ void count_kernel(const int* __restrict__ rows,
                             int* __restrict__ counts, int nnz) {
    int e = (blockIdx.x * blockDim.x + threadIdx.x) * 4;
    if (e + 3 < nnz) {
        int4 r4 = *(const int4*)(rows + e);
        atomicAdd(&counts[r4.x], 1);
        atomicAdd(&counts[r4.y], 1);
        atomicAdd(&counts[r4.z], 1);
        atomicAdd(&counts[r4.w], 1);
    } else {
        for (int k = e; k < nnz; ++k) atomicAdd(&counts[rows[k]], 1);
    }
}

// ---- single-dispatch exclusive scan: 1024 threads x ITEMS=30 items each ----
__global__ void __launch_bounds__(1024)
scan_all_kernel(const int* __restrict__ counts,
                int* __restrict__ offsets,
                int* __restrict__ cursor, int n) {
    const int ITEMS = 30;   // 1024*30 = 30720 >= 30000
    __shared__ int tsum[1024];
    int tid  = threadIdx.x;
    int base = tid * ITEMS;
    int local[ITEMS];
    int s = 0;
#pragma unroll
    for (int k = 0; k < ITEMS; ++k) {
        int idx = base + k;
        int v = (idx < n) ? counts[idx] : 0;
        local[k] = s;
        s += v;
    }
    tsum[tid] = s;
    __syncthreads();
    for (int off = 1; off < 1024; off <<= 1) {
        int t = (tid >= off) ? tsum[tid - off] : 0;
        __syncthreads();
        tsum[tid] += t;
        __syncthreads();
    }
    int texcl = tsum[tid] - s;
#pragma unroll
    for (int k = 0; k < ITEMS; ++k) {
        int idx = base + k;
        if (idx < n) {
            int o = texcl + local[k];
            offsets[idx] = o;
            cursor[idx]  = o;
        }
    }
    if (tid == 1023) offsets[n] = tsum[1023];
}

// one combined 8B store per edge: {col, val-bits}
__global__ void scatter_kernel(const int* __restrict__ rows,
                               const int* __restrict__ cols,
                               const float* __restrict__ vals,
                               int* __restrict__ cursor,
                               uint2* __restrict__ epair, int nnz) {
    int e = blockIdx.x * blockDim.x + threadIdx.x;
    if (e < nnz) {
        int r = rows[e];
        int pos = atomicAdd(&cursor[r], 1);
        epair[pos] = make_uint2((unsigned)cols[e], __float_as_uint(vals[e]));
    }
}

// ---- fused SpMM + renormalize + transpose-out + residual ----
// block = 256 threads (4 waves); block owns 32 rows; wave w does rows w*8..w*8+7.
// lane holds m = 2*lane, 2*lane+1 (one bf16x2 = 4B gather per edge).
__global__ void spmm_fused_kernel(const int* __restrict__ offsets,
                                  const uint2* __restrict__ epair,
                                  const unsigned short* __restrict__ flatTb,
                                  const float* __restrict__ logits,
                                  float* __restrict__ out, int n) {
    __shared__ float tile[128][33];
    const int tid  = threadIdx.x;
    const int wave = tid >> 6;
    const int lane = tid & 63;
    const int r0   = blockIdx.x * 32;

    for (int k = 0; k < 8; ++k) {
        int rl = wave * 8 + k;
        int r  = r0 + rl;
        if (r >= n) break;
        int start = offsets[r];
        int end   = offsets[r + 1];

        float2 a0 = {0.f, 0.f}, a1 = {0.f, 0.f}, a2 = {0.f, 0.f}, a3 = {0.f, 0.f};
        float rsum = 0.f;

        for (int i = start; i < end; i += 64) {
            int idx = i + lane;
            uint2 ed = make_uint2(0u, 0u);
            if (idx < end) ed = epair[idx];
            int   c = (int)ed.x;
            float v = __uint_as_float(ed.y);
            int cnt = end - i;
            if (cnt > 64) cnt = 64;
            int j = 0;
            for (; j + 3 < cnt; j += 4) {
                int   c0 = __shfl(c, j),     c1 = __shfl(c, j + 1);
                int   c2 = __shfl(c, j + 2), c3 = __shfl(c, j + 3);
                float v0 = __shfl(v, j),     v1 = __shfl(v, j + 1);
                float v2 = __shfl(v, j + 2), v3 = __shfl(v, j + 3);
                unsigned int x0 = *((const unsigned int*)(flatTb + (size_t)c0 * 128) + lane);
                unsigned int x1 = *((const unsigned int*)(flatTb + (size_t)c1 * 128) + lane);
                unsigned int x2 = *((const unsigned int*)(flatTb + (size_t)c2 * 128) + lane);
                unsigned int x3 = *((const unsigned int*)(flatTb + (size_t)c3 * 128) + lane);
                a0.x += v0 * __uint_as_float(x0 << 16);
                a0.y += v0 * __uint_as_float(x0 & 0xffff0000u);
                a1.x += v1 * __uint_as_float(x1 << 16);
                a1.y += v1 * __uint_as_float(x1 & 0xffff0000u);
                a2.x += v2 * __uint_as_float(x2 << 16);
                a2.y += v2 * __uint_as_float(x2 & 0xffff0000u);
                a3.x += v3 * __uint_as_float(x3 << 16);
                a3.y += v3 * __uint_as_float(x3 & 0xffff0000u);
                rsum += (v0 + v1) + (v2 + v3);
            }
            for (; j < cnt; ++j) {
                int   cj = __shfl(c, j);
                float vj = __shfl(v, j);
                unsigned int xj = *((const unsigned int*)(flatTb + (size_t)cj * 128) + lane);
                a0.x += vj * __uint_as_float(xj << 16);
                a0.y += vj * __uint_as_float(xj & 0xffff0000u);
                rsum += vj;
            }
        }
        float inv = 1.0f / rsum;
        float ox = (a0.x + a1.x + a2.x + a3.x) * inv;
        float oy = (a0.y + a1.y + a2.y + a3.y) * inv;
        tile[2 * lane][rl]     = ox;
        tile[2 * lane + 1][rl] = oy;
    }
    __syncthreads();

    // write phase: 8 groups x 32 lanes; group g writes m = g*16..g*16+15
    int g = tid >> 5;
    int l = tid & 31;
    int r = r0 + l;
    if (r < n) {
#pragma unroll
        for (int mi = 0; mi < 16; ++mi) {
            int m = g * 16 + mi;
            size_t idx = (size_t)m * n + r;
            out[idx] = tile[m][l] + logits[idx];
        }
    }
}

// ---------------- fallback path (tiny workspace): atomics into d_out -------
__global__ void rowsum_kernel(const int* __restrict__ rows,
                              const float* __restrict__ vals,
                              float* __restrict__ rsum, int nnz) {
    int e = blockIdx.x * blockDim.x + threadIdx.x;
    if (e < nnz) atomicAdd(&rsum[rows[e]], vals[e]);
}

__global__ void zero_float_kernel(float* __restrict__ p, size_t n) {
    size_t i = (size_t)blockIdx.x * blockDim.x + threadIdx.x;
    if (i < n) p[i] = 0.f;
}

__global__ void edge_atomic_kernel(const int* __restrict__ rows,
                                   const int* __restrict__ cols,
                                   const float* __restrict__ vals,
                                   const float* __restrict__ flat,
                                   float* __restrict__ out, int nnz, int n, int m) {
    int e = blockIdx.x * blockDim.x + threadIdx.x;
    if (e < nnz) {
        int r = rows[e], c = cols[e];
        float v = vals[e];
        for (int mm = 0; mm < m; ++mm)
            atomicAdd(&out[(size_t)mm * n + r], v * flat[(size_t)mm * n + c]);
    }
}

__global__ void fallback_final(const float* __restrict__ flat,
                               const float* __restrict__ rsum,
                               float* __restrict__ out, size_t total, int n) {
    size_t i = (size_t)blockIdx.x * blockDim.x + threadIdx.x;
    if (i < total) {
        int nn = (int)(i % n);
        out[i] = out[i] / rsum[nn] + flat[i];
    }
}

extern "C" void kernel_launch(void* const* d_in, const int* in_sizes, int n_in,
                              void* d_out, int out_size, void* d_ws, size_t ws_size,
                              hipStream_t stream) {
    const float* logits = (const float*)d_in[0];
    const int*   adj    = (const int*)d_in[1];
    const float* vals   = (const float*)d_in[2];
    int nnz = in_sizes[2];
    int n   = NCLS;
    int m   = in_sizes[0] / n;     // 128
    const int* rows = adj;
    const int* cols = adj + nnz;
    float* out = (float*)d_out;

    size_t nm = (size_t)n * m;
    // layout: flatTb (bf16, nm*2 B, 8-aligned) | epair (nnz*8 B) | counts | offsets | cursor
    size_t needed_bytes = nm * 2 + (size_t)nnz * 8 + ((size_t)3 * n + 2) * 4 + 64;

    if (m == 128 && ws_size >= needed_bytes) {
        unsigned short* flatTb = (unsigned short*)d_ws;
        uint2* epair    = (uint2*)(flatTb + nm);        // nm*2 divisible by 8
        int*   counts   = (int*)(epair + nnz);
        int*   offsets  = counts + n;
        int*   cursor   = offsets + n + 1;

        dim3 tb(32, 8);
        dim3 tg((n + 31) / 32, m / 32);
        transpose_in_kernel<<<tg, tb, 0, stream>>>(logits, flatTb, counts, n, m);
        count_kernel<<<(nnz / 4 + 255) / 256, 256, 0, stream>>>(rows, counts, nnz);
        scan_all_kernel<<<1, 1024, 0, stream>>>(counts, offsets, cursor, n);
        scatter_kernel<<<(nnz + 255) / 256, 256, 0, stream>>>(rows, cols, vals,
                                                              cursor, epair, nnz);
        spmm_fused_kernel<<<(n + 31) / 32, 256, 0, stream>>>(offsets, epair,
                                                             flatTb, logits, out, n);
    } else {
        // minimal-workspace fallback: atomic scatter into d_out
        float* rsum = (float*)d_ws;
        zero_float_kernel<<<(n + 255) / 256, 256, 0, stream>>>(rsum, (size_t)n);
        zero_float_kernel<<<(int)((nm + 255) / 256), 256, 0, stream>>>(out, nm);
        rowsum_kernel<<<(nnz + 255) / 256, 256, 0, stream>>>(rows, vals, rsum, nnz);
        edge_atomic_kernel<<<(nnz + 255) / 256, 256, 0, stream>>>(rows, cols, vals,
                                                                  logits, out, nnz, n, m);
        size_t total = nm;
        fallback_final<<<(int)((total + 255) / 256), 256, 0, stream>>>(logits, rsum,
                                                                       out, total, n);
    }
}

// Round 8
// 101.473 us; speedup vs baseline: 1.2872x; 1.2872x over previous
//
#include <hip/hip_runtime.h>

#define NCLS 30000

__device__ __forceinline__ unsigned short f2bf(float x) {
    unsigned int u = __float_as_uint(x);
    unsigned int r = (u + 0x7fffu + ((u >> 16) & 1u)) >> 16;   // RNE
    return (unsigned short)r;
}

// ---- transpose logits [M][N] -> flatTb [N][M] in bf16 (M=128);
// ---- blockIdx.y==0 slabs also zero the counts array (done before count pass)
__global__ void transpose_in_kernel(const float* __restrict__ src,
                                    unsigned short* __restrict__ dst,
                                    int* __restrict__ counts, int n, int m) {
    __shared__ float tile[32][33];
    int n0 = blockIdx.x * 32;
    int m0 = blockIdx.y * 32;
    int tx = threadIdx.x, ty = threadIdx.y;   // 32 x 8 threads

    if (blockIdx.y == 0) {
        int t = blockIdx.x * 256 + ty * 32 + tx;
        if (t < n) counts[t] = 0;
    }
#pragma unroll
    for (int k = 0; k < 4; ++k) {
        int mm = m0 + ty + k * 8;
        int nn = n0 + tx;
        if (nn < n) tile[ty + k * 8][tx] = src[(size_t)mm * n + nn];
    }
    __syncthreads();
#pragma unroll
    for (int k = 0; k < 4; ++k) {
        int nn = n0 + ty + k * 8;
        int mm = m0 + tx;
        if (nn < n) dst[(size_t)nn * m + mm] = f2bf(tile[tx][ty + k * 8]);
    }
}

// 4 edges per thread, vectorized row load
__global__ void count_kernel(const int* __restrict__ rows,
                             int* __restrict__ counts, int nnz) {
    int e = (blockIdx.x * blockDim.x + threadIdx.x) * 4;
    if (e + 3 < nnz) {
        int4 r4 = *(const int4*)(rows + e);
        atomicAdd(&counts[r4.x], 1);
        atomicAdd(&counts[r4.y], 1);
        atomicAdd(&counts[r4.z], 1);
        atomicAdd(&counts[r4.w], 1);
    } else {
        for (int k = e; k < nnz; ++k) atomicAdd(&counts[rows[k]], 1);
    }
}

// ---- hierarchical scan: phase 1 — per-block (1024-elem) exclusive scan ----
__global__ void scan1_kernel(const int* __restrict__ counts,
                             int* __restrict__ offsets,
                             int* __restrict__ blocksum, int n) {
    __shared__ int lds[1024];
    int tid = threadIdx.x;
    int gid = blockIdx.x * 1024 + tid;
    int v = (gid < n) ? counts[gid] : 0;
    lds[tid] = v;
    __syncthreads();
    for (int off = 1; off < 1024; off <<= 1) {
        int t = (tid >= off) ? lds[tid - off] : 0;
        __syncthreads();
        lds[tid] += t;
        __syncthreads();
    }
    if (gid < n) offsets[gid] = lds[tid] - v;     // exclusive within block
    if (tid == 1023) blocksum[blockIdx.x] = lds[1023];
}

__global__ void scan2_kernel(int* __restrict__ blocksum, int nb) {
    if (threadIdx.x == 0 && blockIdx.x == 0) {
        int acc = 0;
        for (int i = 0; i < nb; ++i) {
            int t = blocksum[i];
            blocksum[i] = acc;
            acc += t;
        }
        blocksum[nb] = acc;   // grand total
    }
}

__global__ void scan3_kernel(int* __restrict__ offsets,
                             int* __restrict__ cursor,
                             const int* __restrict__ blocksum, int n, int nb) {
    int gid = blockIdx.x * blockDim.x + threadIdx.x;
    if (gid < n) {
        int o = offsets[gid] + blocksum[gid >> 10];
        offsets[gid] = o;
        cursor[gid]  = o;
    } else if (gid == n) {
        offsets[n] = blocksum[nb];
    }
}

// one combined 8B store per edge: {col, val-bits}
__global__ void scatter_kernel(const int* __restrict__ rows,
                               const int* __restrict__ cols,
                               const float* __restrict__ vals,
                               int* __restrict__ cursor,
                               uint2* __restrict__ epair, int nnz) {
    int e = blockIdx.x * blockDim.x + threadIdx.x;
    if (e < nnz) {
        int r = rows[e];
        int pos = atomicAdd(&cursor[r], 1);
        epair[pos] = make_uint2((unsigned)cols[e], __float_as_uint(vals[e]));
    }
}

// ---- fused SpMM + renormalize + transpose-out + residual ----
// block = 256 threads (4 waves); block owns 32 rows; wave w does rows w*8..w*8+7.
// lane holds m = 2*lane, 2*lane+1 (one bf16x2 = 4B gather per edge).
__global__ void spmm_fused_kernel(const int* __restrict__ offsets,
                                  const uint2* __restrict__ epair,
                                  const unsigned short* __restrict__ flatTb,
                                  const float* __restrict__ logits,
                                  float* __restrict__ out, int n) {
    __shared__ float tile[128][33];
    const int tid  = threadIdx.x;
    const int wave = tid >> 6;
    const int lane = tid & 63;
    const int r0   = blockIdx.x * 32;

    for (int k = 0; k < 8; ++k) {
        int rl = wave * 8 + k;
        int r  = r0 + rl;
        if (r >= n) break;
        int start = offsets[r];
        int end   = offsets[r + 1];

        float2 a0 = {0.f, 0.f}, a1 = {0.f, 0.f}, a2 = {0.f, 0.f}, a3 = {0.f, 0.f};
        float rsum = 0.f;

        for (int i = start; i < end; i += 64) {
            int idx = i + lane;
            uint2 ed = make_uint2(0u, 0u);
            if (idx < end) ed = epair[idx];
            int   c = (int)ed.x;
            float v = __uint_as_float(ed.y);
            int cnt = end - i;
            if (cnt > 64) cnt = 64;
            int j = 0;
            for (; j + 3 < cnt; j += 4) {
                int   c0 = __shfl(c, j),     c1 = __shfl(c, j + 1);
                int   c2 = __shfl(c, j + 2), c3 = __shfl(c, j + 3);
                float v0 = __shfl(v, j),     v1 = __shfl(v, j + 1);
                float v2 = __shfl(v, j + 2), v3 = __shfl(v, j + 3);
                unsigned int x0 = *((const unsigned int*)(flatTb + (size_t)c0 * 128) + lane);
                unsigned int x1 = *((const unsigned int*)(flatTb + (size_t)c1 * 128) + lane);
                unsigned int x2 = *((const unsigned int*)(flatTb + (size_t)c2 * 128) + lane);
                unsigned int x3 = *((const unsigned int*)(flatTb + (size_t)c3 * 128) + lane);
                a0.x += v0 * __uint_as_float(x0 << 16);
                a0.y += v0 * __uint_as_float(x0 & 0xffff0000u);
                a1.x += v1 * __uint_as_float(x1 << 16);
                a1.y += v1 * __uint_as_float(x1 & 0xffff0000u);
                a2.x += v2 * __uint_as_float(x2 << 16);
                a2.y += v2 * __uint_as_float(x2 & 0xffff0000u);
                a3.x += v3 * __uint_as_float(x3 << 16);
                a3.y += v3 * __uint_as_float(x3 & 0xffff0000u);
                rsum += (v0 + v1) + (v2 + v3);
            }
            for (; j < cnt; ++j) {
                int   cj = __shfl(c, j);
                float vj = __shfl(v, j);
                unsigned int xj = *((const unsigned int*)(flatTb + (size_t)cj * 128) + lane);
                a0.x += vj * __uint_as_float(xj << 16);
                a0.y += vj * __uint_as_float(xj & 0xffff0000u);
                rsum += vj;
            }
        }
        float inv = 1.0f / rsum;
        float ox = (a0.x + a1.x + a2.x + a3.x) * inv;
        float oy = (a0.y + a1.y + a2.y + a3.y) * inv;
        tile[2 * lane][rl]     = ox;
        tile[2 * lane + 1][rl] = oy;
    }
    __syncthreads();

    // write phase: 8 groups x 32 lanes; group g writes m = g*16..g*16+15
    int g = tid >> 5;
    int l = tid & 31;
    int r = r0 + l;
    if (r < n) {
#pragma unroll
        for (int mi = 0; mi < 16; ++mi) {
            int m = g * 16 + mi;
            size_t idx = (size_t)m * n + r;
            out[idx] = tile[m][l] + logits[idx];
        }
    }
}

// ---------------- fallback path (tiny workspace): atomics into d_out -------
__global__ void rowsum_kernel(const int* __restrict__ rows,
                              const float* __restrict__ vals,
                              float* __restrict__ rsum, int nnz) {
    int e = blockIdx.x * blockDim.x + threadIdx.x;
    if (e < nnz) atomicAdd(&rsum[rows[e]], vals[e]);
}

__global__ void zero_float_kernel(float* __restrict__ p, size_t n) {
    size_t i = (size_t)blockIdx.x * blockDim.x + threadIdx.x;
    if (i < n) p[i] = 0.f;
}

__global__ void edge_atomic_kernel(const int* __restrict__ rows,
                                   const int* __restrict__ cols,
                                   const float* __restrict__ vals,
                                   const float* __restrict__ flat,
                                   float* __restrict__ out, int nnz, int n, int m) {
    int e = blockIdx.x * blockDim.x + threadIdx.x;
    if (e < nnz) {
        int r = rows[e], c = cols[e];
        float v = vals[e];
        for (int mm = 0; mm < m; ++mm)
            atomicAdd(&out[(size_t)mm * n + r], v * flat[(size_t)mm * n + c]);
    }
}

__global__ void fallback_final(const float* __restrict__ flat,
                               const float* __restrict__ rsum,
                               float* __restrict__ out, size_t total, int n) {
    size_t i = (size_t)blockIdx.x * blockDim.x + threadIdx.x;
    if (i < total) {
        int nn = (int)(i % n);
        out[i] = out[i] / rsum[nn] + flat[i];
    }
}

extern "C" void kernel_launch(void* const* d_in, const int* in_sizes, int n_in,
                              void* d_out, int out_size, void* d_ws, size_t ws_size,
                              hipStream_t stream) {
    const float* logits = (const float*)d_in[0];
    const int*   adj    = (const int*)d_in[1];
    const float* vals   = (const float*)d_in[2];
    int nnz = in_sizes[2];
    int n   = NCLS;
    int m   = in_sizes[0] / n;     // 128
    const int* rows = adj;
    const int* cols = adj + nnz;
    float* out = (float*)d_out;

    size_t nm = (size_t)n * m;
    int nb = (n + 1023) / 1024;    // scan blocks
    // layout: flatTb | epair | counts | offsets | cursor | blocksum
    size_t needed_bytes = nm * 2 + (size_t)nnz * 8
                        + ((size_t)3 * n + 2 + (size_t)(nb + 1)) * 4 + 64;

    if (m == 128 && ws_size >= needed_bytes) {
        unsigned short* flatTb = (unsigned short*)d_ws;
        uint2* epair    = (uint2*)(flatTb + nm);        // nm*2 divisible by 8
        int*   counts   = (int*)(epair + nnz);
        int*   offsets  = counts + n;
        int*   cursor   = offsets + n + 1;
        int*   blocksum = cursor + n;

        dim3 tb(32, 8);
        dim3 tg((n + 31) / 32, m / 32);
        transpose_in_kernel<<<tg, tb, 0, stream>>>(logits, flatTb, counts, n, m);
        count_kernel<<<(nnz / 4 + 255) / 256, 256, 0, stream>>>(rows, counts, nnz);
        scan1_kernel<<<nb, 1024, 0, stream>>>(counts, offsets, blocksum, n);
        scan2_kernel<<<1, 64, 0, stream>>>(blocksum, nb);
        scan3_kernel<<<(n + 1 + 255) / 256, 256, 0, stream>>>(offsets, cursor,
                                                              blocksum, n, nb);
        scatter_kernel<<<(nnz + 255) / 256, 256, 0, stream>>>(rows, cols, vals,
                                                              cursor, epair, nnz);
        spmm_fused_kernel<<<(n + 31) / 32, 256, 0, stream>>>(offsets, epair,
                                                             flatTb, logits, out, n);
    } else {
        // minimal-workspace fallback: atomic scatter into d_out
        float* rsum = (float*)d_ws;
        zero_float_kernel<<<(n + 255) / 256, 256, 0, stream>>>(rsum, (size_t)n);
        zero_float_kernel<<<(int)((nm + 255) / 256), 256, 0, stream>>>(out, nm);
        rowsum_kernel<<<(nnz + 255) / 256, 256, 0, stream>>>(rows, vals, rsum, nnz);
        edge_atomic_kernel<<<(nnz + 255) / 256, 256, 0, stream>>>(rows, cols, vals,
                                                                  logits, out, nnz, n, m);
        size_t total = nm;
        fallback_final<<<(int)((total + 255) / 256), 256, 0, stream>>>(logits, rsum,
                                                                       out, total, n);
    }
}

// Round 9
// 98.094 us; speedup vs baseline: 1.3315x; 1.0344x over previous
//
#include <hip/hip_runtime.h>

#define NCLS 30000

__device__ __forceinline__ unsigned short f2bf(float x) {
    unsigned int u = __float_as_uint(x);
    unsigned int r = (u + 0x7fffu + ((u >> 16) & 1u)) >> 16;   // RNE
    return (unsigned short)r;
}

// ---- transpose logits [M][N] -> flatTb [N][M] in bf16 (M=128);
// ---- blockIdx.y==0 slabs also zero the counts array (done before count pass)
__global__ void transpose_in_kernel(const float* __restrict__ src,
                                    unsigned short* __restrict__ dst,
                                    int* __restrict__ counts, int n, int m) {
    __shared__ float tile[32][33];
    int n0 = blockIdx.x * 32;
    int m0 = blockIdx.y * 32;
    int tx = threadIdx.x, ty = threadIdx.y;   // 32 x 8 threads

    if (blockIdx.y == 0) {
        int t = blockIdx.x * 256 + ty * 32 + tx;
        if (t < n) counts[t] = 0;
    }
#pragma unroll
    for (int k = 0; k < 4; ++k) {
        int mm = m0 + ty + k * 8;
        int nn = n0 + tx;
        if (nn < n) tile[ty + k * 8][tx] = src[(size_t)mm * n + nn];
    }
    __syncthreads();
#pragma unroll
    for (int k = 0; k < 4; ++k) {
        int nn = n0 + ty + k * 8;
        int mm = m0 + tx;
        if (nn < n) dst[(size_t)nn * m + mm] = f2bf(tile[tx][ty + k * 8]);
    }
}

// 4 edges per thread, vectorized row load
__global__ void count_kernel(const int* __restrict__ rows,
                             int* __restrict__ counts, int nnz) {
    int e = (blockIdx.x * blockDim.x + threadIdx.x) * 4;
    if (e + 3 < nnz) {
        int4 r4 = *(const int4*)(rows + e);
        atomicAdd(&counts[r4.x], 1);
        atomicAdd(&counts[r4.y], 1);
        atomicAdd(&counts[r4.z], 1);
        atomicAdd(&counts[r4.w], 1);
    } else {
        for (int k = e; k < nnz; ++k) atomicAdd(&counts[rows[k]], 1);
    }
}

// ---- hierarchical scan: phase 1 — per-block (1024-elem) exclusive scan ----
__global__ void scan1_kernel(const int* __restrict__ counts,
                             int* __restrict__ offsets,
                             int* __restrict__ blocksum, int n) {
    __shared__ int lds[1024];
    int tid = threadIdx.x;
    int gid = blockIdx.x * 1024 + tid;
    int v = (gid < n) ? counts[gid] : 0;
    lds[tid] = v;
    __syncthreads();
    for (int off = 1; off < 1024; off <<= 1) {
        int t = (tid >= off) ? lds[tid - off] : 0;
        __syncthreads();
        lds[tid] += t;
        __syncthreads();
    }
    if (gid < n) offsets[gid] = lds[tid] - v;     // exclusive within block
    if (tid == 1023) blocksum[blockIdx.x] = lds[1023];
}

// ---- phase 2+3 fused: each block computes its slab carry from blocksum ----
__global__ void scan3_kernel(int* __restrict__ offsets,
                             int* __restrict__ cursor,
                             const int* __restrict__ blocksum, int n, int nb) {
    __shared__ int bsum[64];
    int tid = threadIdx.x;
    for (int i = tid; i < nb; i += 256) bsum[i] = blocksum[i];
    __syncthreads();
    int gid  = blockIdx.x * 256 + tid;
    int slab = (blockIdx.x * 256) >> 10;          // 256 | 1024 -> uniform slab
    int carry = 0;
    for (int i = 0; i < slab; ++i) carry += bsum[i];   // LDS broadcast reads
    if (gid < n) {
        int o = offsets[gid] + carry;
        offsets[gid] = o;
        cursor[gid]  = o;
    } else if (gid == n) {
        int total = 0;
        for (int i = 0; i < nb; ++i) total += bsum[i];
        offsets[n] = total;
    }
}

// one combined 8B store per edge: {col, val-bits}
__global__ void scatter_kernel(const int* __restrict__ rows,
                               const int* __restrict__ cols,
                               const float* __restrict__ vals,
                               int* __restrict__ cursor,
                               uint2* __restrict__ epair, int nnz) {
    int e = blockIdx.x * blockDim.x + threadIdx.x;
    if (e < nnz) {
        int r = rows[e];
        int pos = atomicAdd(&cursor[r], 1);
        epair[pos] = make_uint2((unsigned)cols[e], __float_as_uint(vals[e]));
    }
}

// ---- fused SpMM + renormalize + transpose-out + residual ----
// block = 256 threads (4 waves); block owns 32 rows; wave w does rows w*8..w*8+7.
// Edge stream is wave-uniform: start/end forced to SGPR, epair loads have
// uniform addresses (scalar path), gathers are saddr + lane*4 -> no shfls.
__global__ void spmm_fused_kernel(const int* __restrict__ offsets,
                                  const uint2* __restrict__ epair,
                                  const unsigned short* __restrict__ flatTb,
                                  const float* __restrict__ logits,
                                  float* __restrict__ out, int n) {
    __shared__ float tile[128][33];
    const int tid  = threadIdx.x;
    const int wave = tid >> 6;
    const int lane = tid & 63;
    const int r0   = blockIdx.x * 32;

    for (int k = 0; k < 8; ++k) {
        int rl = wave * 8 + k;
        int r  = r0 + rl;
        if (r >= n) break;
        int start = __builtin_amdgcn_readfirstlane(offsets[r]);
        int end   = __builtin_amdgcn_readfirstlane(offsets[r + 1]);

        float2 a0 = {0.f, 0.f}, a1 = {0.f, 0.f}, a2 = {0.f, 0.f}, a3 = {0.f, 0.f};
        float rsum = 0.f;

        int i = start;
        for (; i + 3 < end; i += 4) {
            uint2 e0 = epair[i];
            uint2 e1 = epair[i + 1];
            uint2 e2 = epair[i + 2];
            uint2 e3 = epair[i + 3];
            float v0 = __uint_as_float(e0.y), v1 = __uint_as_float(e1.y);
            float v2 = __uint_as_float(e2.y), v3 = __uint_as_float(e3.y);
            unsigned int x0 = *((const unsigned int*)(flatTb + (size_t)e0.x * 128) + lane);
            unsigned int x1 = *((const unsigned int*)(flatTb + (size_t)e1.x * 128) + lane);
            unsigned int x2 = *((const unsigned int*)(flatTb + (size_t)e2.x * 128) + lane);
            unsigned int x3 = *((const unsigned int*)(flatTb + (size_t)e3.x * 128) + lane);
            a0.x += v0 * __uint_as_float(x0 << 16);
            a0.y += v0 * __uint_as_float(x0 & 0xffff0000u);
            a1.x += v1 * __uint_as_float(x1 << 16);
            a1.y += v1 * __uint_as_float(x1 & 0xffff0000u);
            a2.x += v2 * __uint_as_float(x2 << 16);
            a2.y += v2 * __uint_as_float(x2 & 0xffff0000u);
            a3.x += v3 * __uint_as_float(x3 << 16);
            a3.y += v3 * __uint_as_float(x3 & 0xffff0000u);
            rsum += (v0 + v1) + (v2 + v3);
        }
        for (; i < end; ++i) {
            uint2 ej = epair[i];
            float vj = __uint_as_float(ej.y);
            unsigned int xj = *((const unsigned int*)(flatTb + (size_t)ej.x * 128) + lane);
            a0.x += vj * __uint_as_float(xj << 16);
            a0.y += vj * __uint_as_float(xj & 0xffff0000u);
            rsum += vj;
        }
        float inv = 1.0f / rsum;
        float ox = (a0.x + a1.x + a2.x + a3.x) * inv;
        float oy = (a0.y + a1.y + a2.y + a3.y) * inv;
        tile[2 * lane][rl]     = ox;
        tile[2 * lane + 1][rl] = oy;
    }
    __syncthreads();

    // write phase: 8 groups x 32 lanes; group g writes m = g*16..g*16+15
    int g = tid >> 5;
    int l = tid & 31;
    int r = r0 + l;
    if (r < n) {
#pragma unroll
        for (int mi = 0; mi < 16; ++mi) {
            int m = g * 16 + mi;
            size_t idx = (size_t)m * n + r;
            out[idx] = tile[m][l] + logits[idx];
        }
    }
}

// ---------------- fallback path (tiny workspace): atomics into d_out -------
__global__ void rowsum_kernel(const int* __restrict__ rows,
                              const float* __restrict__ vals,
                              float* __restrict__ rsum, int nnz) {
    int e = blockIdx.x * blockDim.x + threadIdx.x;
    if (e < nnz) atomicAdd(&rsum[rows[e]], vals[e]);
}

__global__ void zero_float_kernel(float* __restrict__ p, size_t n) {
    size_t i = (size_t)blockIdx.x * blockDim.x + threadIdx.x;
    if (i < n) p[i] = 0.f;
}

__global__ void edge_atomic_kernel(const int* __restrict__ rows,
                                   const int* __restrict__ cols,
                                   const float* __restrict__ vals,
                                   const float* __restrict__ flat,
                                   float* __restrict__ out, int nnz, int n, int m) {
    int e = blockIdx.x * blockDim.x + threadIdx.x;
    if (e < nnz) {
        int r = rows[e], c = cols[e];
        float v = vals[e];
        for (int mm = 0; mm < m; ++mm)
            atomicAdd(&out[(size_t)mm * n + r], v * flat[(size_t)mm * n + c]);
    }
}

__global__ void fallback_final(const float* __restrict__ flat,
                               const float* __restrict__ rsum,
                               float* __restrict__ out, size_t total, int n) {
    size_t i = (size_t)blockIdx.x * blockDim.x + threadIdx.x;
    if (i < total) {
        int nn = (int)(i % n);
        out[i] = out[i] / rsum[nn] + flat[i];
    }
}

extern "C" void kernel_launch(void* const* d_in, const int* in_sizes, int n_in,
                              void* d_out, int out_size, void* d_ws, size_t ws_size,
                              hipStream_t stream) {
    const float* logits = (const float*)d_in[0];
    const int*   adj    = (const int*)d_in[1];
    const float* vals   = (const float*)d_in[2];
    int nnz = in_sizes[2];
    int n   = NCLS;
    int m   = in_sizes[0] / n;     // 128
    const int* rows = adj;
    const int* cols = adj + nnz;
    float* out = (float*)d_out;

    size_t nm = (size_t)n * m;
    int nb = (n + 1023) / 1024;    // scan blocks (30)
    // layout: flatTb | epair | counts | offsets | cursor | blocksum
    size_t needed_bytes = nm * 2 + (size_t)nnz * 8
                        + ((size_t)3 * n + 2 + (size_t)(nb + 1)) * 4 + 64;

    if (m == 128 && nb <= 64 && ws_size >= needed_bytes) {
        unsigned short* flatTb = (unsigned short*)d_ws;
        uint2* epair    = (uint2*)(flatTb + nm);        // nm*2 divisible by 8
        int*   counts   = (int*)(epair + nnz);
        int*   offsets  = counts + n;
        int*   cursor   = offsets + n + 1;
        int*   blocksum = cursor + n;

        dim3 tb(32, 8);
        dim3 tg((n + 31) / 32, m / 32);
        transpose_in_kernel<<<tg, tb, 0, stream>>>(logits, flatTb, counts, n, m);
        count_kernel<<<(nnz / 4 + 255) / 256, 256, 0, stream>>>(rows, counts, nnz);
        scan1_kernel<<<nb, 1024, 0, stream>>>(counts, offsets, blocksum, n);
        scan3_kernel<<<(n + 1 + 255) / 256, 256, 0, stream>>>(offsets, cursor,
                                                              blocksum, n, nb);
        scatter_kernel<<<(nnz + 255) / 256, 256, 0, stream>>>(rows, cols, vals,
                                                              cursor, epair, nnz);
        spmm_fused_kernel<<<(n + 31) / 32, 256, 0, stream>>>(offsets, epair,
                                                             flatTb, logits, out, n);
    } else {
        // minimal-workspace fallback: atomic scatter into d_out
        float* rsum = (float*)d_ws;
        zero_float_kernel<<<(n + 255) / 256, 256, 0, stream>>>(rsum, (size_t)n);
        zero_float_kernel<<<(int)((nm + 255) / 256), 256, 0, stream>>>(out, nm);
        rowsum_kernel<<<(nnz + 255) / 256, 256, 0, stream>>>(rows, vals, rsum, nnz);
        edge_atomic_kernel<<<(nnz + 255) / 256, 256, 0, stream>>>(rows, cols, vals,
                                                                  logits, out, nnz, n, m);
        size_t total = nm;
        fallback_final<<<(int)((total + 255) / 256), 256, 0, stream>>>(logits, rsum,
                                                                       out, total, n);
    }
}